// Round 6
// baseline (1003.298 us; speedup 1.0000x reference)
//
#include <hip/hip_runtime.h>

#define BB 256
#define TT 1024
#define II 128
#define HH 64
#define BT (BB * TT)

typedef _Float16 h2 __attribute__((ext_vector_type(2)));
typedef _Float16 half8 __attribute__((ext_vector_type(8)));
typedef float f32x4 __attribute__((ext_vector_type(4)));
typedef unsigned int uint;
typedef unsigned short ushort;

#define BC(u) __builtin_bit_cast(h2, (uint)(u))
#define MFMA16(a, b, c) __builtin_amdgcn_mfma_f32_16x16x32_f16((a), (b), (c), 0, 0, 0)
#define SIG(v) __builtin_amdgcn_rcpf(1.0f + __expf(-(v)))
#define TNH(v) (1.0f - 2.0f * __builtin_amdgcn_rcpf(1.0f + __expf(2.0f * (v))))

// barrier per step (R15: cross-half h-coupling requires it); lgkm-only drain
#define BAR() asm volatile("s_waitcnt lgkmcnt(0)\n\ts_barrier" ::: "memory")

__device__ __forceinline__ uint pk2(float a, float b) {
    h2 h; h[0] = (_Float16)a; h[1] = (_Float16)b;
    return __builtin_bit_cast(uint, h);
}

// ============ Kernel B: 8-wave fused recurrence (R15) =======================
// R15: every role is SPLIT across 2 waves by output half (j in [wh*32,+32)),
// halving each wave's serial MFMA chain (32 -> 16 per step) and putting 2
// waves on every SIMD so MFMA issue interleaves (single-wave cadence ~16cy
// was the R12-measured core floor). 8 waves = 512 thr, waves_per_eu(2,2):
//   w0,w1 (P0,P1):   h0(k)   = lstm0(xgb(k), h0(k-1))      [W_hh0, tiles 8/wave]
//   w2,w3 (Q1a,b):   z(k-1)  = W_ih1 . h0(k-1)             [W_ih1]
//   w4,w5 (Q2a,b):   h1(k-2) = act(z(k-2)+W_hh1.h1(k-3)+b) [W_hh1]
//   w6,w7 (W0,W1):   xgb window (k>>4)+1, 1 tile / 2 steps [w_ih0 via LDS]
// Tile algebra: gate g of unit j=wh*32+jl lives in LOCAL tile (jl>>4)*4+g,
// col jl&15 = lane&15 -> extraction is ONE v_cndmask per gate.
// Barrier per step; all cross-wave edges cross >=1 barrier:
//   h0(k): written step k (both halves), read step k+1 (P,Q1)   [2-deep]
//   z(m):  written step m+1 (Q1), read step m+2 (Q2)            [2-deep]
//   h1(m): written step m+2 (Q2 halves), read step m+3          [2-deep]
//   xgb(w): written during window w-1's 16 steps, read window w [2-deep]
// All MFMA chains/operands identical to R14 -> bit-identical output.
__global__ __launch_bounds__(512) __attribute__((amdgpu_waves_per_eu(2, 2)))
void lstm2_core(const float* __restrict__ x, const float* __restrict__ w_ih0,
                const float* __restrict__ w_hh0,
                const float* __restrict__ b_ih0, const float* __restrict__ b_hh0,
                const float* __restrict__ w_ih1, const float* __restrict__ w_hh1,
                const float* __restrict__ b_ih1, const float* __restrict__ b_hh1,
                ushort* __restrict__ h1g)
{
    const int bb   = blockIdx.x;
    const int tid  = threadIdx.x;
    const int w    = tid >> 6;
    const int role = w >> 1;          // 0=P 1=Q1 2=Q2 3=W
    const int wh   = w & 1;           // output half
    const int ln   = tid & 63;
    const int qq   = ln >> 4, cc = ln & 15;
    const int jl   = ln & 31;         // local unit (lanes 32-63 duplicate)
    const int j    = wh * 32 + jl;    // owned unit
    const int sel  = (ln >> 4) & 1;   // tile-group select within half
    const bool lo32 = (ln < 32);

    __shared__ __align__(16) uint   h0buf[2][32];
    __shared__ __align__(16) uint   h1buf[2][32];
    __shared__ __align__(16) float  zbuf[2][64][4];
    __shared__ __align__(16) ushort xgb[2][16][264];     // row pad vs bank alias
    __shared__ __align__(16) uint4  wfrag[16][4][4][16]; // w_ih0 B-frags, 64KB

    // ---- stage w_ih0 -> f16 MFMA B-frags: wave w does tiles (w>>2)*8..+8,
    //      k-chunk w&3; perm(flat)=(flat&3)*64+(flat>>2) => col 4j+g = gate g of j
    {
        const int kc = w & 3;
        #pragma unroll
        for (int t = 0; t < 8; ++t) {
            const int T = (w >> 2) * 8 + t;
            const int flat = T * 16 + cc;
            const int srcrow = (flat & 3) * 64 + (flat >> 2);
            const float* p = w_ih0 + (size_t)srcrow * II + kc * 32 + qq * 8;
            uint4 v;
            v.x = pk2(p[0], p[1]); v.y = pk2(p[2], p[3]);
            v.z = pk2(p[4], p[5]); v.w = pk2(p[6], p[7]);
            wfrag[T][kc][qq][cc] = v;
        }
    }

    // ---- recurrent-weight fragments: 8 LOCAL tiles x 2 k-halves per wave ----
    uint4 Bf[8][2];
    if (role < 3) {
        const float* Wsel = (role == 0) ? w_hh0 : (role == 1) ? w_ih1 : w_hh1;
        #pragma unroll
        for (int t = 0; t < 8; ++t) {
            const int T = wh * 8 + t;
            const int row = (T & 3) * 64 + (T >> 2) * 16 + cc;
            const float* rp = Wsel + (size_t)row * 64 + qq * 8;
            #pragma unroll
            for (int kh = 0; kh < 2; ++kh) {
                const float* p = rp + kh * 32;
                uint4 v;
                v.x = pk2(p[0], p[1]); v.y = pk2(p[2], p[3]);
                v.z = pk2(p[4], p[5]); v.w = pk2(p[6], p[7]);
                Bf[t][kh] = v;
            }
        }
    }

    float bI = 0.f, bF = 0.f, bG = 0.f, bO = 0.f;
    if (role == 0) {
        bI = b_ih0[j]       + b_hh0[j];
        bF = b_ih0[64 + j]  + b_hh0[64 + j];
        bG = b_ih0[128 + j] + b_hh0[128 + j];
        bO = b_ih0[192 + j] + b_hh0[192 + j];
    } else if (role == 2) {
        bI = b_ih1[j]       + b_hh1[j];
        bF = b_ih1[64 + j]  + b_hh1[64 + j];
        bG = b_ih1[128 + j] + b_hh1[128 + j];
        bO = b_ih1[192 + j] + b_hh1[192 + j];
    }

    float cst = 0.0f;
    const float* xrow = x + (size_t)bb * TT * II;
    ushort* h1b = h1g + (size_t)bb * TT * 64 + j;

    const f32x4 ZR4 = {0.f, 0.f, 0.f, 0.f};

    half8 af0 = {0,0,0,0,0,0,0,0}, af1 = af0;
    float4 xr[8] = {};
    half8 wa0 = af0, wa1 = af0, wa2 = af0, wa3 = af0;

#define XLOAD(WND) if ((WND) < 64) { \
    const float* xp_ = xrow + (size_t)((WND) * 16 + cc) * II + qq * 8; \
    xr[0] = *(const float4*)(xp_ +  0); xr[1] = *(const float4*)(xp_ +  4); \
    xr[2] = *(const float4*)(xp_ + 32); xr[3] = *(const float4*)(xp_ + 36); \
    xr[4] = *(const float4*)(xp_ + 64); xr[5] = *(const float4*)(xp_ + 68); \
    xr[6] = *(const float4*)(xp_ + 96); xr[7] = *(const float4*)(xp_ + 100); }

#define MKAF4() { uint4 u_; \
    u_.x = pk2(xr[0].x, xr[0].y); u_.y = pk2(xr[0].z, xr[0].w); \
    u_.z = pk2(xr[1].x, xr[1].y); u_.w = pk2(xr[1].z, xr[1].w); \
    wa0 = __builtin_bit_cast(half8, u_); \
    u_.x = pk2(xr[2].x, xr[2].y); u_.y = pk2(xr[2].z, xr[2].w); \
    u_.z = pk2(xr[3].x, xr[3].y); u_.w = pk2(xr[3].z, xr[3].w); \
    wa1 = __builtin_bit_cast(half8, u_); \
    u_.x = pk2(xr[4].x, xr[4].y); u_.y = pk2(xr[4].z, xr[4].w); \
    u_.z = pk2(xr[5].x, xr[5].y); u_.w = pk2(xr[5].z, xr[5].w); \
    wa2 = __builtin_bit_cast(half8, u_); \
    u_.x = pk2(xr[6].x, xr[6].y); u_.y = pk2(xr[6].z, xr[6].w); \
    u_.z = pk2(xr[7].x, xr[7].y); u_.w = pk2(xr[7].z, xr[7].w); \
    wa3 = __builtin_bit_cast(half8, u_); }

#define WTILEH(T, BUF) { \
    f32x4 d_ = ZR4; \
    d_ = MFMA16(wa0, __builtin_bit_cast(half8, wfrag[T][0][qq][cc]), d_); \
    d_ = MFMA16(wa1, __builtin_bit_cast(half8, wfrag[T][1][qq][cc]), d_); \
    d_ = MFMA16(wa2, __builtin_bit_cast(half8, wfrag[T][2][qq][cc]), d_); \
    d_ = MFMA16(wa3, __builtin_bit_cast(half8, wfrag[T][3][qq][cc]), d_); \
    _Pragma("unroll") \
    for (int r_ = 0; r_ < 4; ++r_) { \
        _Float16 hv_ = (_Float16)d_[r_]; \
        xgb[BUF][qq * 4 + r_][(T) * 16 + cc] = __builtin_bit_cast(ushort, hv_); } }

    __syncthreads();                       // wfrag ready
    if (role == 3) {                       // W prologue: window 0 + load x(1)
        XLOAD(0)
        MKAF4()
        #pragma unroll
        for (int t = 0; t < 8; ++t) WTILEH(wh * 8 + t, 0)
        XLOAD(1)
    } else if (tid < 32)       h0buf[1][tid] = 0u;       // h0(-1) = 0
    else if (tid >= 64 && tid < 96) h1buf[1][tid - 64] = 0u; // h1(-1) = 0
    __syncthreads();

#define LDAF(SRC) { const char* hb_ = (const char*)(SRC); \
    af0 = *(const half8*)(hb_ + (qq << 4)); \
    af1 = *(const half8*)(hb_ + 64 + (qq << 4)); }

#define GEMV8(SI, SF, SG, SO) { \
    f32x4 D[8]; \
    _Pragma("unroll") \
    for (int t = 0; t < 8; ++t) { \
        f32x4 d_ = MFMA16(af0, __builtin_bit_cast(half8, Bf[t][0]), ZR4); \
        D[t] = MFMA16(af1, __builtin_bit_cast(half8, Bf[t][1]), d_); } \
    SI = sel ? D[4][0] : D[0][0]; \
    SF = sel ? D[5][0] : D[1][0]; \
    SG = sel ? D[6][0] : D[2][0]; \
    SO = sel ? D[7][0] : D[3][0]; }

    for (int k = 0; k < TT + 2; ++k) {
        if (role == 0) {
            // ---- P: h0(k) from h0(k-1) ----
            if (k < TT) {
                LDAF(&h0buf[(k + 1) & 1][0])                    // h0(k-1)
                const uint2 xcv = *(const uint2*)&xgb[(k >> 4) & 1][k & 15][j * 4];
                float si, sf, sg, so;
                GEMV8(si, sf, sg, so)
                h2 xlo = BC(xcv.x), xhi = BC(xcv.y);
                si += bI + (float)xlo[0]; sf += bF + (float)xlo[1];
                sg += bG + (float)xhi[0]; so += bO + (float)xhi[1];
                float ii = SIG(si), ff = SIG(sf), gg = TNH(sg), oo = SIG(so);
                cst = fmaf(ff, cst, ii * gg);
                float hval = oo * TNH(cst);
                if (lo32) ((_Float16*)&h0buf[k & 1][0])[j] = (_Float16)hval;
            }
        } else if (role == 1) {
            // ---- Q1: z(m) = W_ih1 . h0(m), m = k-1 ----
            if (k >= 1 && k <= TT) {
                const int m = k - 1;
                LDAF(&h0buf[m & 1][0])
                float si, sf, sg, so;
                GEMV8(si, sf, sg, so)
                if (lo32) {
                    f32x4 zv = {si, sf, sg, so};
                    *(f32x4*)&zbuf[m & 1][j][0] = zv;
                }
            }
        } else if (role == 2) {
            // ---- Q2: h1(m) from z(m), h1(m-1), m = k-2 ----
            if (k >= 2) {
                const int m = k - 2;
                LDAF(&h1buf[(m + 1) & 1][0])                    // h1(m-1)
                const f32x4 zr = *(const f32x4*)&zbuf[m & 1][j][0];
                float si, sf, sg, so;
                GEMV8(si, sf, sg, so)
                si += bI + zr[0]; sf += bF + zr[1];
                sg += bG + zr[2]; so += bO + zr[3];
                float ii = SIG(si), ff = SIG(sf), gg = TNH(sg), oo = SIG(so);
                cst = fmaf(ff, cst, ii * gg);
                float hval = oo * TNH(cst);
                _Float16 hf = (_Float16)hval;
                if (lo32) {
                    ((_Float16*)&h1buf[m & 1][0])[j] = hf;
                    h1b[(size_t)m * 64] = __builtin_bit_cast(ushort, hf);
                }
            }
        } else {
            // ---- W: window (k>>4)+1, one tile every other step ----
            const int sl = k & 15;
            const int wnd = (k >> 4) + 1;
            if (sl == 0) {
                if (wnd < 64) { MKAF4() }
                XLOAD(wnd + 1)
            }
            if (wnd < 64 && !(sl & 1)) {
                const int t = sl >> 1;
                WTILEH(wh * 8 + t, wnd & 1)
            }
        }
        BAR();
    }
#undef GEMV8
#undef LDAF
#undef WTILEH
#undef MKAF4
#undef XLOAD
}

// ============ Kernel C: out[bt] = sigmoid(h1g[bt,:] . w_out + b_out) =========
__global__ __launch_bounds__(256)
void head_gemv(const ushort* __restrict__ h1g, const float* __restrict__ w_out,
               const float* __restrict__ b_out, float* __restrict__ outp)
{
    __shared__ float wsh[64];
    const int tid = threadIdx.x;
    if (tid < 64) wsh[tid] = w_out[tid];
    __syncthreads();
    const int bt = blockIdx.x * 256 + tid;
    const uint4* hp = (const uint4*)(h1g + (size_t)bt * 64);
    float s = 0.0f;
    #pragma unroll
    for (int i = 0; i < 8; ++i) {
        uint4 v = hp[i];
        const float* wp = &wsh[8 * i];
        h2 p;
        p = BC(v.x); s = fmaf((float)p[0], wp[0], s); s = fmaf((float)p[1], wp[1], s);
        p = BC(v.y); s = fmaf((float)p[0], wp[2], s); s = fmaf((float)p[1], wp[3], s);
        p = BC(v.z); s = fmaf((float)p[0], wp[4], s); s = fmaf((float)p[1], wp[5], s);
        p = BC(v.w); s = fmaf((float)p[0], wp[6], s); s = fmaf((float)p[1], wp[7], s);
    }
    outp[bt] = __builtin_amdgcn_rcpf(1.0f + __expf(-(s + b_out[0])));
}

extern "C" void kernel_launch(void* const* d_in, const int* in_sizes, int n_in,
                              void* d_out, int out_size, void* d_ws, size_t ws_size,
                              hipStream_t stream) {
    const float* x     = (const float*)d_in[0];
    const float* w_ih0 = (const float*)d_in[1];
    const float* w_hh0 = (const float*)d_in[2];
    const float* b_ih0 = (const float*)d_in[3];
    const float* b_hh0 = (const float*)d_in[4];
    const float* w_ih1 = (const float*)d_in[5];
    const float* w_hh1 = (const float*)d_in[6];
    const float* b_ih1 = (const float*)d_in[7];
    const float* b_hh1 = (const float*)d_in[8];
    const float* w_out = (const float*)d_in[9];
    const float* b_out = (const float*)d_in[10];
    float* out = (float*)d_out;

    ushort* h1g = (ushort*)d_ws;   // 32 MiB

    hipLaunchKernelGGL(lstm2_core, dim3(BB), dim3(512), 0, stream,
                       x, w_ih0, w_hh0, b_ih0, b_hh0,
                       w_ih1, w_hh1, b_ih1, b_hh1, h1g);
    hipLaunchKernelGGL(head_gemv, dim3(BT / 256), dim3(256), 0, stream,
                       h1g, w_out, b_out, out);
}

// Round 8
// 833.008 us; speedup vs baseline: 1.2044x; 1.2044x over previous
//
#include <hip/hip_runtime.h>

#define BB 256
#define TT 1024
#define II 128
#define HH 64
#define BT (BB * TT)

typedef _Float16 h2 __attribute__((ext_vector_type(2)));
typedef _Float16 half8 __attribute__((ext_vector_type(8)));
typedef float f32x4 __attribute__((ext_vector_type(4)));
typedef unsigned int uint;
typedef unsigned short ushort;

#define BC(u) __builtin_bit_cast(h2, (uint)(u))
#define MFMA16(a, b, c) __builtin_amdgcn_mfma_f32_16x16x32_f16((a), (b), (c), 0, 0, 0)
#define SIG(v) __builtin_amdgcn_rcpf(1.0f + __expf(-(v)))
#define TNH(v) (1.0f - 2.0f * __builtin_amdgcn_rcpf(1.0f + __expf(2.0f * (v))))

// one barrier per 2 steps, lgkm-only drain (R11/R12-verified schedule)
#define BAR() asm volatile("s_waitcnt lgkmcnt(0)\n\ts_barrier" ::: "memory")

__device__ __forceinline__ uint pk2(float a, float b) {
    h2 h; h[0] = (_Float16)a; h[1] = (_Float16)b;
    return __builtin_bit_cast(uint, h);
}

// ============ Kernel A: xg[b][j][t][g] = x[b,t,:] . w_ih0[g*64+j,:]  (f16) ==
// (R13-verified: LDS-staged epilogue, [b][j][t][g] layout, W-row permute)
__global__ __launch_bounds__(256)
void xg_mfma(const float* __restrict__ x, const float* __restrict__ w_ih0,
             ushort* __restrict__ xg)
{
    __shared__ __align__(16) _Float16 xt[64][136];
    __shared__ __align__(16) _Float16 wt[128][136];
    __shared__ __align__(16) ushort   sg[64][140];
    const int tid = threadIdx.x, lane = tid & 63, wv = tid >> 6;
    const int bt0 = blockIdx.x * 64;
    const int b = bt0 >> 10, t0 = bt0 & 1023;
    {
        const int row = tid >> 2, q = (tid & 3) * 32;
        const float4* src = (const float4*)(x + (size_t)(bt0 + row) * II + q);
        _Float16* dst = &xt[row][q];
        #pragma unroll
        for (int i = 0; i < 8; ++i) {
            float4 v = src[i];
            dst[4*i+0]=(_Float16)v.x; dst[4*i+1]=(_Float16)v.y;
            dst[4*i+2]=(_Float16)v.z; dst[4*i+3]=(_Float16)v.w;
        }
    }
    for (int nh = 0; nh < 2; ++nh) {
        __syncthreads();
        {
            const int n = tid >> 1, kh = (tid & 1) * 64;
            const int flatn = nh * 128 + n;
            const int srcrow = (flatn & 3) * 64 + (flatn >> 2);
            const float4* src = (const float4*)(w_ih0 + (size_t)srcrow * II + kh);
            _Float16* dst = &wt[n][kh];
            #pragma unroll
            for (int i = 0; i < 16; ++i) {
                float4 v = src[i];
                dst[4*i+0]=(_Float16)v.x; dst[4*i+1]=(_Float16)v.y;
                dst[4*i+2]=(_Float16)v.z; dst[4*i+3]=(_Float16)v.w;
            }
        }
        __syncthreads();
        const int m = wv * 16 + (lane & 15);
        const int kf = (lane >> 4) * 8;
        half8 a0 = *(const half8*)&xt[m][ 0 + kf];
        half8 a1 = *(const half8*)&xt[m][32 + kf];
        half8 a2 = *(const half8*)&xt[m][64 + kf];
        half8 a3 = *(const half8*)&xt[m][96 + kf];
        #pragma unroll
        for (int nt = 0; nt < 8; ++nt) {
            const int nloc = nt * 16 + (lane & 15);
            half8 b0 = *(const half8*)&wt[nloc][ 0 + kf];
            half8 b1 = *(const half8*)&wt[nloc][32 + kf];
            half8 b2 = *(const half8*)&wt[nloc][64 + kf];
            half8 b3 = *(const half8*)&wt[nloc][96 + kf];
            f32x4 acc = {0.f, 0.f, 0.f, 0.f};
            acc = MFMA16(a0, b0, acc); acc = MFMA16(a1, b1, acc);
            acc = MFMA16(a2, b2, acc); acc = MFMA16(a3, b3, acc);
            const int cl = nt * 16 + (lane & 15);
            const int r0 = wv * 16 + (lane >> 4) * 4;
            #pragma unroll
            for (int r = 0; r < 4; ++r) {
                _Float16 hv = (_Float16)acc[r];
                sg[r0 + r][cl] = __builtin_bit_cast(ushort, hv);
            }
        }
        __syncthreads();
        {
            const int jl = tid >> 3, part = tid & 7;
            const int j = nh * 32 + jl;
            ushort* gdst = xg + (((size_t)b * 64 + j) << 12)
                              + (size_t)(t0 + part * 8) * 4;
            #pragma unroll
            for (int i = 0; i < 4; ++i) {
                uint2 lo = *(const uint2*)&sg[part * 8 + 2*i    ][jl * 4];
                uint2 hi = *(const uint2*)&sg[part * 8 + 2*i + 1][jl * 4];
                uint4 v; v.x = lo.x; v.y = lo.y; v.z = hi.x; v.w = hi.y;
                *(uint4*)(gdst + i * 8) = v;
            }
        }
    }
}

// ============ Kernel B: 3 role waves + 1 store wave (R16) ====================
// Base = R12 (503us verified). Surgical changes only:
//  1. GEMV16 split into two 16-wide INDEPENDENT MFMA passes (pass1: all
//     af0*Bf[t][0] from zero; pass2: all af1*Bf[t][1] accumulating) — deps
//     land 16 instrs apart instead of adjacent, attacking the measured
//     16.5cy/MFMA single-wave cadence. Per-tile chain order unchanged ->
//     bit-identical results.
//  2. Wave 3 (S) = store flusher. Q2 writes h1 into an 8-deep LDS ring
//     (also its own A-frag readback buffer); S drains 2 rows/pair to global
//     as one coalesced dword/lane. Q2 sheds its per-step global store (and
//     any store-drain at the barrier moves to S's slack timeline).
//  3. Pinned zero quad Zq for acc-init (targets the v_accvgpr_write storm).
// Ring safety: h1(m) written by Q2 at pair (m+6)>>1; S reads m0=k0-10,k0-9
// at pair k0>>1 (>=2 barriers after write); slot reused at m+8 (2 pairs after
// S's read). Loop extended to TT+10 to flush the tail; Q2 guarded i_<TT+6.
__global__ __launch_bounds__(256) __attribute__((amdgpu_waves_per_eu(1, 1)))
void lstm2_core(const float* __restrict__ w_hh0,
                const float* __restrict__ b_ih0, const float* __restrict__ b_hh0,
                const float* __restrict__ w_ih1, const float* __restrict__ w_hh1,
                const float* __restrict__ b_ih1, const float* __restrict__ b_hh1,
                const ushort* __restrict__ xg, ushort* __restrict__ h1g)
{
    const int bb = blockIdx.x;
    const int w  = threadIdx.x >> 6;
    const int j  = threadIdx.x & 63;
    const int qq = j >> 4, cc = j & 15;

    __shared__ __align__(16) uint  h0buf[8][32];     // 8-deep, 64 f16 each
    __shared__ __align__(16) uint  h1q[8][32];       // 8-deep h1 ring (f16)
    __shared__ __align__(16) float zbuf[8][64][4];   // 8-deep float4/lane

    uint4 Bf[16][2];
    if (w < 3) {
        const float* Wsel = (w == 0) ? w_hh0 : (w == 1) ? w_ih1 : w_hh1;
        #pragma unroll
        for (int t = 0; t < 16; ++t) {
            const int row = (t & 3) * 64 + (t >> 2) * 16 + cc;
            const float* rp = Wsel + (size_t)row * 64 + qq * 8;
            #pragma unroll
            for (int kh = 0; kh < 2; ++kh) {
                const float* p = rp + kh * 32;
                uint4 v;
                v.x = pk2(p[0], p[1]); v.y = pk2(p[2], p[3]);
                v.z = pk2(p[4], p[5]); v.w = pk2(p[6], p[7]);
                Bf[t][kh] = v;
            }
        }
    }

    float bI = 0.f, bF = 0.f, bG = 0.f, bO = 0.f;
    if (w == 0) {
        bI = b_ih0[j]       + b_hh0[j];
        bF = b_ih0[64 + j]  + b_hh0[64 + j];
        bG = b_ih0[128 + j] + b_hh0[128 + j];
        bO = b_ih0[192 + j] + b_hh0[192 + j];
    } else if (w == 2) {
        bI = b_ih1[j]       + b_hh1[j];
        bF = b_ih1[64 + j]  + b_hh1[64 + j];
        bG = b_ih1[128 + j] + b_hh1[128 + j];
        bO = b_ih1[192 + j] + b_hh1[192 + j];
    }

    float cst = 0.0f;
    const ushort* xb = xg + ((size_t)(bb * 64 + j) << 12);   // [b][j][t][g]
    uint* h1w = (uint*)(h1g + (size_t)bb * TT * 64);

    // pinned zero quad: built from opaque zeros so it stays in 4 VGPRs and is
    // REUSED as C-input by all 16 pass-1 MFMAs (vs per-tile accvgpr zero-init)
    float z0 = 0.f, z1 = 0.f, z2 = 0.f, z3 = 0.f;
    asm volatile("" : "+v"(z0), "+v"(z1), "+v"(z2), "+v"(z3));
    const f32x4 Zq = {z0, z1, z2, z3};

    const int qlo = qq & 1, qhi = qq >> 1;

    half8 af0 = {0,0,0,0,0,0,0,0}, af1 = {0,0,0,0,0,0,0,0};
    f32x4 zr = {0.f, 0.f, 0.f, 0.f};
    uint4 q0 = {0,0,0,0}, q1 = {0,0,0,0};
    if (w == 0) {
        q0 = *(const uint4*)(xb);          // pair 0: steps 0,1
        q1 = *(const uint4*)(xb + 8);      // pair 1: steps 2,3
    }

#define LDAF(SRC) { const char* hb_ = (const char*)(SRC); \
    af0 = *(const half8*)(hb_ + (qq << 4)); \
    af1 = *(const half8*)(hb_ + 64 + (qq << 4)); }

// two-pass GEMV: pass1 = 16 independent MFMAs from Zq; pass2 = 16 MFMAs each
// depending on its pass1 partner 16 instructions upstream (latency hidden).
#define GEMV16(SI, SF, SG, SO) { \
    f32x4 D[16]; \
    _Pragma("unroll") \
    for (int t = 0; t < 16; ++t) \
        D[t] = MFMA16(af0, __builtin_bit_cast(half8, Bf[t][0]), Zq); \
    _Pragma("unroll") \
    for (int t = 0; t < 16; ++t) \
        D[t] = MFMA16(af1, __builtin_bit_cast(half8, Bf[t][1]), D[t]); \
    { float a_, b_; \
      a_ = qlo ? D[ 4][0] : D[ 0][0]; b_ = qlo ? D[12][0] : D[ 8][0]; SI = qhi ? b_ : a_; \
      a_ = qlo ? D[ 5][0] : D[ 1][0]; b_ = qlo ? D[13][0] : D[ 9][0]; SF = qhi ? b_ : a_; \
      a_ = qlo ? D[ 6][0] : D[ 2][0]; b_ = qlo ? D[14][0] : D[10][0]; SG = qhi ? b_ : a_; \
      a_ = qlo ? D[ 7][0] : D[ 3][0]; b_ = qlo ? D[15][0] : D[11][0]; SO = qhi ? b_ : a_; } }

#define PSTEP(KK, XLO, XHI) \
    if ((KK) < TT) { \
        float si, sf, sg, so; \
        GEMV16(si, sf, sg, so) \
        h2 xlo = BC(XLO), xhi = BC(XHI); \
        si += bI + (float)xlo[0]; sf += bF + (float)xlo[1]; \
        sg += bG + (float)xhi[0]; so += bO + (float)xhi[1]; \
        float ii = SIG(si), ff = SIG(sf), gg = TNH(sg), oo = SIG(so); \
        cst = fmaf(ff, cst, ii * gg); \
        float hval = oo * TNH(cst); \
        ((_Float16*)&h0buf[(KK) & 7][0])[j] = (_Float16)hval; \
        LDAF(&h0buf[(KK) & 7][0]) \
    }

#define Q1STEP(KK) { const int i_ = (KK); \
    if (i_ >= 3 && i_ < TT + 3) { \
        const int m_ = i_ - 3; \
        float si, sf, sg, so; \
        GEMV16(si, sf, sg, so) \
        f32x4 zv = {si, sf, sg, so}; \
        *(f32x4*)&zbuf[m_ & 7][j][0] = zv; \
    } \
    if (i_ >= 2 && i_ < TT + 2) LDAF(&h0buf[(i_ - 2) & 7][0]) }

#define Q2STEP(KK) { const int i_ = (KK); \
    if (i_ >= 6 && i_ < TT + 6) { \
        const int m_ = i_ - 6; \
        float si, sf, sg, so; \
        GEMV16(si, sf, sg, so) \
        si += bI + zr[0]; sf += bF + zr[1]; \
        sg += bG + zr[2]; so += bO + zr[3]; \
        float ii = SIG(si), ff = SIG(sf), gg = TNH(sg), oo = SIG(so); \
        cst = fmaf(ff, cst, ii * gg); \
        float hval = oo * TNH(cst); \
        _Float16 hf = (_Float16)hval; \
        ((_Float16*)&h1q[m_ & 7][0])[j] = hf; \
        LDAF(&h1q[m_ & 7][0]) \
    } \
    if (i_ >= 5 && i_ < TT + 5) zr = *(const f32x4*)&zbuf[(i_ - 5) & 7][j][0]; }

    for (int k0 = 0; k0 < TT + 10; k0 += 2) {
        if (w == 0) {
            uint4 qn = q1;
            if (k0 + 4 < TT)
                qn = *(const uint4*)(xb + (size_t)(k0 + 4) * 4);
            PSTEP(k0,     q0.x, q0.y)
            PSTEP(k0 + 1, q0.z, q0.w)
            q0 = q1; q1 = qn;
        } else if (w == 1) {
            Q1STEP(k0)
            Q1STEP(k0 + 1)
        } else if (w == 2) {
            Q2STEP(k0)
            Q2STEP(k0 + 1)
        } else {
            // S: flush h1(m0), h1(m0+1) -> one coalesced dword per lane
            if (k0 >= 10) {
                const int m0 = k0 - 10;
                const uint v = ((const uint*)h1q)[((m0 & 7) << 5) + j];
                h1w[((size_t)m0 << 5) + j] = v;
            }
        }
        BAR();
    }
#undef PSTEP
#undef Q1STEP
#undef Q2STEP
#undef GEMV16
#undef LDAF
}

// ============ Kernel C: out[bt] = sigmoid(h1g[bt,:] . w_out + b_out) =========
__global__ __launch_bounds__(256)
void head_gemv(const ushort* __restrict__ h1g, const float* __restrict__ w_out,
               const float* __restrict__ b_out, float* __restrict__ outp)
{
    __shared__ float wsh[64];
    const int tid = threadIdx.x;
    if (tid < 64) wsh[tid] = w_out[tid];
    __syncthreads();
    const int bt = blockIdx.x * 256 + tid;
    const uint4* hp = (const uint4*)(h1g + (size_t)bt * 64);
    float s = 0.0f;
    #pragma unroll
    for (int i = 0; i < 8; ++i) {
        uint4 v = hp[i];
        const float* wp = &wsh[8 * i];
        h2 p;
        p = BC(v.x); s = fmaf((float)p[0], wp[0], s); s = fmaf((float)p[1], wp[1], s);
        p = BC(v.y); s = fmaf((float)p[0], wp[2], s); s = fmaf((float)p[1], wp[3], s);
        p = BC(v.z); s = fmaf((float)p[0], wp[4], s); s = fmaf((float)p[1], wp[5], s);
        p = BC(v.w); s = fmaf((float)p[0], wp[6], s); s = fmaf((float)p[1], wp[7], s);
    }
    outp[bt] = __builtin_amdgcn_rcpf(1.0f + __expf(-(s + b_out[0])));
}

extern "C" void kernel_launch(void* const* d_in, const int* in_sizes, int n_in,
                              void* d_out, int out_size, void* d_ws, size_t ws_size,
                              hipStream_t stream) {
    const float* x     = (const float*)d_in[0];
    const float* w_ih0 = (const float*)d_in[1];
    const float* w_hh0 = (const float*)d_in[2];
    const float* b_ih0 = (const float*)d_in[3];
    const float* b_hh0 = (const float*)d_in[4];
    const float* w_ih1 = (const float*)d_in[5];
    const float* w_hh1 = (const float*)d_in[6];
    const float* b_ih1 = (const float*)d_in[7];
    const float* b_hh1 = (const float*)d_in[8];
    const float* w_out = (const float*)d_in[9];
    const float* b_out = (const float*)d_in[10];
    float* out = (float*)d_out;

    ushort* xg  = (ushort*)d_ws;                                   // 128 MiB
    ushort* h1g = (ushort*)((char*)d_ws + (size_t)BT * 256 * 2);   //  32 MiB

    hipLaunchKernelGGL(xg_mfma, dim3(BT / 64), dim3(256), 0, stream, x, w_ih0, xg);
    hipLaunchKernelGGL(lstm2_core, dim3(BB), dim3(256), 0, stream,
                       w_hh0, b_ih0, b_hh0, w_ih1, w_hh1, b_ih1, b_hh1, xg, h1g);
    hipLaunchKernelGGL(head_gemv, dim3(BT / 256), dim3(256), 0, stream,
                       h1g, w_out, b_out, out);
}

// Round 9
// 808.000 us; speedup vs baseline: 1.2417x; 1.0310x over previous
//
#include <hip/hip_runtime.h>

#define BB 256
#define TT 1024
#define II 128
#define HH 64
#define BT (BB * TT)

typedef _Float16 h2 __attribute__((ext_vector_type(2)));
typedef _Float16 half8 __attribute__((ext_vector_type(8)));
typedef float f32x4 __attribute__((ext_vector_type(4)));
typedef unsigned int uint;
typedef unsigned short ushort;

#define BC(u) __builtin_bit_cast(h2, (uint)(u))
#define MFMA16(a, b, c) __builtin_amdgcn_mfma_f32_16x16x32_f16((a), (b), (c), 0, 0, 0)
#define SIG(v) __builtin_amdgcn_rcpf(1.0f + __expf(-(v)))
#define TNH(v) (1.0f - 2.0f * __builtin_amdgcn_rcpf(1.0f + __expf(2.0f * (v))))

// barrier per step (R18: 4-way output split needs per-step h exchange);
// lgkm-only drain — all cross-wave data flows through LDS.
#define BAR() asm volatile("s_waitcnt lgkmcnt(0)\n\ts_barrier" ::: "memory")

__device__ __forceinline__ uint pk2(float a, float b) {
    h2 h; h[0] = (_Float16)a; h[1] = (_Float16)b;
    return __builtin_bit_cast(uint, h);
}

// ============ Kernel A: xg[b][j][t][g] = x[b,t,:] . w_ih0[g*64+j,:]  (f16) ==
// (R13-verified: LDS-staged epilogue, [b][j][t][g] layout, W-row permute)
__global__ __launch_bounds__(256)
void xg_mfma(const float* __restrict__ x, const float* __restrict__ w_ih0,
             ushort* __restrict__ xg)
{
    __shared__ __align__(16) _Float16 xt[64][136];
    __shared__ __align__(16) _Float16 wt[128][136];
    __shared__ __align__(16) ushort   sg[64][140];
    const int tid = threadIdx.x, lane = tid & 63, wv = tid >> 6;
    const int bt0 = blockIdx.x * 64;
    const int b = bt0 >> 10, t0 = bt0 & 1023;
    {
        const int row = tid >> 2, q = (tid & 3) * 32;
        const float4* src = (const float4*)(x + (size_t)(bt0 + row) * II + q);
        _Float16* dst = &xt[row][q];
        #pragma unroll
        for (int i = 0; i < 8; ++i) {
            float4 v = src[i];
            dst[4*i+0]=(_Float16)v.x; dst[4*i+1]=(_Float16)v.y;
            dst[4*i+2]=(_Float16)v.z; dst[4*i+3]=(_Float16)v.w;
        }
    }
    for (int nh = 0; nh < 2; ++nh) {
        __syncthreads();
        {
            const int n = tid >> 1, kh = (tid & 1) * 64;
            const int flatn = nh * 128 + n;
            const int srcrow = (flatn & 3) * 64 + (flatn >> 2);
            const float4* src = (const float4*)(w_ih0 + (size_t)srcrow * II + kh);
            _Float16* dst = &wt[n][kh];
            #pragma unroll
            for (int i = 0; i < 16; ++i) {
                float4 v = src[i];
                dst[4*i+0]=(_Float16)v.x; dst[4*i+1]=(_Float16)v.y;
                dst[4*i+2]=(_Float16)v.z; dst[4*i+3]=(_Float16)v.w;
            }
        }
        __syncthreads();
        const int m = wv * 16 + (lane & 15);
        const int kf = (lane >> 4) * 8;
        half8 a0 = *(const half8*)&xt[m][ 0 + kf];
        half8 a1 = *(const half8*)&xt[m][32 + kf];
        half8 a2 = *(const half8*)&xt[m][64 + kf];
        half8 a3 = *(const half8*)&xt[m][96 + kf];
        #pragma unroll
        for (int nt = 0; nt < 8; ++nt) {
            const int nloc = nt * 16 + (lane & 15);
            half8 b0 = *(const half8*)&wt[nloc][ 0 + kf];
            half8 b1 = *(const half8*)&wt[nloc][32 + kf];
            half8 b2 = *(const half8*)&wt[nloc][64 + kf];
            half8 b3 = *(const half8*)&wt[nloc][96 + kf];
            f32x4 acc = {0.f, 0.f, 0.f, 0.f};
            acc = MFMA16(a0, b0, acc); acc = MFMA16(a1, b1, acc);
            acc = MFMA16(a2, b2, acc); acc = MFMA16(a3, b3, acc);
            const int cl = nt * 16 + (lane & 15);
            const int r0 = wv * 16 + (lane >> 4) * 4;
            #pragma unroll
            for (int r = 0; r < 4; ++r) {
                _Float16 hv = (_Float16)acc[r];
                sg[r0 + r][cl] = __builtin_bit_cast(ushort, hv);
            }
        }
        __syncthreads();
        {
            const int jl = tid >> 3, part = tid & 7;
            const int j = nh * 32 + jl;
            ushort* gdst = xg + (((size_t)b * 64 + j) << 12)
                              + (size_t)(t0 + part * 8) * 4;
            #pragma unroll
            for (int i = 0; i < 4; ++i) {
                uint2 lo = *(const uint2*)&sg[part * 8 + 2*i    ][jl * 4];
                uint2 hi = *(const uint2*)&sg[part * 8 + 2*i + 1][jl * 4];
                uint4 v; v.x = lo.x; v.y = lo.y; v.z = hi.x; v.w = hi.y;
                *(uint4*)(gdst + i * 8) = v;
            }
        }
    }
}

// ============ Kernel B: 12-wave recurrence, 4-way-split GEMV (R18) ===========
// R16 proved per-MFMA pipe occupancy ~16.5cy/SIMD is a HW throughput limit
// (MFMA-busy invariant under dependency restructuring; matches 19.4cy µbench).
// => single wave issuing 32 MFMA/step has a 528cy floor. Fix: split every
// role's GEMV 4 ways by output range. Wave w: role=w>>2 (0=P,1=Q1,2=Q2),
// part p=w&3 owns units j=p*16+cc via tiles 4p..4p+3. Tile algebra: tile
// (4p+g) row = g*64 + p*16 + cc  => the wave's 4 tiles are EXACTLY gates
// 0..3 of its 16 units — si=D0[0],sf=D1[0],sg=D2[0],so=D3[0], no selection.
// 12 waves = 3/SIMD; each SIMD hosts {P_p,Q1_p,Q2_p} = 24 MFMA/step ~ 396cy.
// Barrier per step; lags: P(k) | Q1: z(k-2) | Q2: h1(k-4); 4-deep buffers =>
// every cross-wave edge >=1 barrier, slot reuse >=2 steps after last read.
// MFMA chains and act formulas identical to R12 -> same absmax.
__global__ __launch_bounds__(768) __attribute__((amdgpu_waves_per_eu(3, 3)))
void lstm2_core(const float* __restrict__ w_hh0,
                const float* __restrict__ b_ih0, const float* __restrict__ b_hh0,
                const float* __restrict__ w_ih1, const float* __restrict__ w_hh1,
                const float* __restrict__ b_ih1, const float* __restrict__ b_hh1,
                const ushort* __restrict__ xg, ushort* __restrict__ h1g)
{
    const int bb   = blockIdx.x;
    const int tid  = threadIdx.x;
    const int w    = tid >> 6;
    const int role = w >> 2;          // 0=P, 1=Q1, 2=Q2
    const int p    = w & 3;           // output part
    const int ln   = tid & 63;
    const int qq   = ln >> 4, cc = ln & 15;
    const int j    = p * 16 + cc;     // owned unit
    const bool wr  = (ln < 16);       // writer lane group

    __shared__ __align__(16) uint  h0buf[4][32];   // 4-deep, 64 f16
    __shared__ __align__(16) uint  h1buf[4][32];   // 4-deep, 64 f16
    __shared__ __align__(16) float zbuf[4][64][4]; // 4-deep float4 per unit

    // ---- weight fragments: 4 tiles (gates 0..3 of units p*16..p*16+15) ----
    const float* Wsel = (role == 0) ? w_hh0 : (role == 1) ? w_ih1 : w_hh1;
    uint4 Bf00, Bf01, Bf10, Bf11, Bf20, Bf21, Bf30, Bf31;
#define LDBF(G, V0, V1) { \
    const float* rp = Wsel + (size_t)((G) * 64 + j) * 64 + qq * 8; \
    { const float* pp = rp;       uint4 v; \
      v.x = pk2(pp[0], pp[1]); v.y = pk2(pp[2], pp[3]); \
      v.z = pk2(pp[4], pp[5]); v.w = pk2(pp[6], pp[7]); V0 = v; } \
    { const float* pp = rp + 32;  uint4 v; \
      v.x = pk2(pp[0], pp[1]); v.y = pk2(pp[2], pp[3]); \
      v.z = pk2(pp[4], pp[5]); v.w = pk2(pp[6], pp[7]); V1 = v; } }
    LDBF(0, Bf00, Bf01) LDBF(1, Bf10, Bf11)
    LDBF(2, Bf20, Bf21) LDBF(3, Bf30, Bf31)
#undef LDBF

    // ---- biases: P -> layer0, Q2 -> layer1, Q1 -> zeros ----
    float bI = 0.f, bF = 0.f, bG = 0.f, bO = 0.f;
    if (role == 0) {
        bI = b_ih0[j]       + b_hh0[j];
        bF = b_ih0[64 + j]  + b_hh0[64 + j];
        bG = b_ih0[128 + j] + b_hh0[128 + j];
        bO = b_ih0[192 + j] + b_hh0[192 + j];
    } else if (role == 2) {
        bI = b_ih1[j]       + b_hh1[j];
        bF = b_ih1[64 + j]  + b_hh1[64 + j];
        bG = b_ih1[128 + j] + b_hh1[128 + j];
        bO = b_ih1[192 + j] + b_hh1[192 + j];
    }

    float cst = 0.0f;                                  // P / Q2 cell state
    const ushort* xb = xg + ((size_t)(bb * 64 + j) << 12);   // [b][j][t][g]
    ushort* h1b = h1g + (size_t)bb * TT * 64 + j;

    half8 af0 = {0,0,0,0,0,0,0,0}, af1 = af0;
    uint4 q0 = {0,0,0,0}, q1 = {0,0,0,0};
    if (role == 0) {
        q0 = *(const uint4*)(xb);          // steps 0,1
        q1 = *(const uint4*)(xb + 8);      // steps 2,3
    }

    // zero-init the step -1 slots (slot 3)
    if (tid < 32)                 h0buf[3][tid] = 0u;
    else if (tid < 64)            h1buf[3][tid - 32] = 0u;
    __syncthreads();

#define LDAF(SRC) { const char* hb_ = (const char*)(SRC); \
    af0 = *(const half8*)(hb_ + (qq << 4)); \
    af1 = *(const half8*)(hb_ + 64 + (qq << 4)); }

#define GEMV4(SI, SF, SG, SO) { \
    const f32x4 Z_ = {0.f, 0.f, 0.f, 0.f}; \
    f32x4 D0 = MFMA16(af0, __builtin_bit_cast(half8, Bf00), Z_); \
    f32x4 D1 = MFMA16(af0, __builtin_bit_cast(half8, Bf10), Z_); \
    f32x4 D2 = MFMA16(af0, __builtin_bit_cast(half8, Bf20), Z_); \
    f32x4 D3 = MFMA16(af0, __builtin_bit_cast(half8, Bf30), Z_); \
    D0 = MFMA16(af1, __builtin_bit_cast(half8, Bf01), D0); \
    D1 = MFMA16(af1, __builtin_bit_cast(half8, Bf11), D1); \
    D2 = MFMA16(af1, __builtin_bit_cast(half8, Bf21), D2); \
    D3 = MFMA16(af1, __builtin_bit_cast(half8, Bf31), D3); \
    SI = D0[0]; SF = D1[0]; SG = D2[0]; SO = D3[0]; }

// P: h0(K) = lstm0(xg(K), h0(K-1))
#define PBODY(K, XLO, XHI) { \
    LDAF(&h0buf[((K) + 3) & 3][0]) \
    float si, sf, sg, so; \
    GEMV4(si, sf, sg, so) \
    h2 xlo = BC(XLO), xhi = BC(XHI); \
    si += bI + (float)xlo[0]; sf += bF + (float)xlo[1]; \
    sg += bG + (float)xhi[0]; so += bO + (float)xhi[1]; \
    float ii = SIG(si), ff = SIG(sf), gg = TNH(sg), oo = SIG(so); \
    cst = fmaf(ff, cst, ii * gg); \
    float hval = oo * TNH(cst); \
    if (wr) ((_Float16*)&h0buf[(K) & 3][0])[j] = (_Float16)hval; }

// Q1: z(M) = W_ih1 . h0(M)   (raw gate sums, no bias — added by Q2)
#define Q1BODY(M) { \
    LDAF(&h0buf[(M) & 3][0]) \
    float si, sf, sg, so; \
    GEMV4(si, sf, sg, so) \
    if (wr) { f32x4 zv = {si, sf, sg, so}; \
              *(f32x4*)&zbuf[(M) & 3][j][0] = zv; } }

// Q2: h1(M) = act(z(M) + W_hh1 . h1(M-1) + b)
#define Q2BODY(M) { \
    LDAF(&h1buf[((M) + 3) & 3][0]) \
    const f32x4 zr = *(const f32x4*)&zbuf[(M) & 3][j][0]; \
    float si, sf, sg, so; \
    GEMV4(si, sf, sg, so) \
    si += bI + zr[0]; sf += bF + zr[1]; \
    sg += bG + zr[2]; so += bO + zr[3]; \
    float ii = SIG(si), ff = SIG(sf), gg = TNH(sg), oo = SIG(so); \
    cst = fmaf(ff, cst, ii * gg); \
    float hval = oo * TNH(cst); \
    _Float16 hf = (_Float16)hval; \
    if (wr) { ((_Float16*)&h1buf[(M) & 3][0])[j] = hf; \
              h1b[(size_t)(M) * 64] = __builtin_bit_cast(ushort, hf); } }

    for (int k0 = 0; k0 < TT + 4; k0 += 2) {
        uint4 qn = q1;
        // ---- even step k = k0 ----
        if (role == 0) {
            if (k0 + 4 < TT) qn = *(const uint4*)(xb + (size_t)(k0 + 4) * 4);
            if (k0 < TT) PBODY(k0, q0.x, q0.y)
        } else if (role == 1) {
            if (k0 >= 2 && k0 < TT + 2) Q1BODY(k0 - 2)
        } else {
            if (k0 >= 4) Q2BODY(k0 - 4)
        }
        BAR();
        // ---- odd step k = k0 + 1 ----
        if (role == 0) {
            if (k0 + 1 < TT) PBODY(k0 + 1, q0.z, q0.w)
            q0 = q1; q1 = qn;
        } else if (role == 1) {
            if (k0 + 1 >= 2 && k0 + 1 < TT + 2) Q1BODY(k0 - 1)
        } else {
            if (k0 + 1 >= 4) Q2BODY(k0 - 3)
        }
        BAR();
    }
#undef PBODY
#undef Q1BODY
#undef Q2BODY
#undef GEMV4
#undef LDAF
}

// ============ Kernel C: out[bt] = sigmoid(h1g[bt,:] . w_out + b_out) =========
__global__ __launch_bounds__(256)
void head_gemv(const ushort* __restrict__ h1g, const float* __restrict__ w_out,
               const float* __restrict__ b_out, float* __restrict__ outp)
{
    __shared__ float wsh[64];
    const int tid = threadIdx.x;
    if (tid < 64) wsh[tid] = w_out[tid];
    __syncthreads();
    const int bt = blockIdx.x * 256 + tid;
    const uint4* hp = (const uint4*)(h1g + (size_t)bt * 64);
    float s = 0.0f;
    #pragma unroll
    for (int i = 0; i < 8; ++i) {
        uint4 v = hp[i];
        const float* wp = &wsh[8 * i];
        h2 p;
        p = BC(v.x); s = fmaf((float)p[0], wp[0], s); s = fmaf((float)p[1], wp[1], s);
        p = BC(v.y); s = fmaf((float)p[0], wp[2], s); s = fmaf((float)p[1], wp[3], s);
        p = BC(v.z); s = fmaf((float)p[0], wp[4], s); s = fmaf((float)p[1], wp[5], s);
        p = BC(v.w); s = fmaf((float)p[0], wp[6], s); s = fmaf((float)p[1], wp[7], s);
    }
    outp[bt] = __builtin_amdgcn_rcpf(1.0f + __expf(-(s + b_out[0])));
}

extern "C" void kernel_launch(void* const* d_in, const int* in_sizes, int n_in,
                              void* d_out, int out_size, void* d_ws, size_t ws_size,
                              hipStream_t stream) {
    const float* x     = (const float*)d_in[0];
    const float* w_ih0 = (const float*)d_in[1];
    const float* w_hh0 = (const float*)d_in[2];
    const float* b_ih0 = (const float*)d_in[3];
    const float* b_hh0 = (const float*)d_in[4];
    const float* w_ih1 = (const float*)d_in[5];
    const float* w_hh1 = (const float*)d_in[6];
    const float* b_ih1 = (const float*)d_in[7];
    const float* b_hh1 = (const float*)d_in[8];
    const float* w_out = (const float*)d_in[9];
    const float* b_out = (const float*)d_in[10];
    float* out = (float*)d_out;

    ushort* xg  = (ushort*)d_ws;                                   // 128 MiB
    ushort* h1g = (ushort*)((char*)d_ws + (size_t)BT * 256 * 2);   //  32 MiB

    hipLaunchKernelGGL(xg_mfma, dim3(BT / 64), dim3(256), 0, stream, x, w_ih0, xg);
    hipLaunchKernelGGL(lstm2_core, dim3(BB), dim3(768), 0, stream,
                       w_hh0, b_ih0, b_hh0, w_ih1, w_hh1, b_ih1, b_hh1, xg, h1g);
    hipLaunchKernelGGL(head_gemv, dim3(BT / 256), dim3(256), 0, stream,
                       h1g, w_out, b_out, out);
}